// Round 3
// baseline (3863.267 us; speedup 1.0000x reference)
//
#include <hip/hip_runtime.h>

#define HID   64
#define SEQ   512
#define BBLK  4
#define NTHR  512
#define NBLK  256

typedef _Float16 h2v __attribute__((ext_vector_type(2)));

#if defined(__has_builtin)
#  if __has_builtin(__builtin_amdgcn_fdot2)
#    define HAVE_FDOT2 1
#  endif
#endif

__device__ __forceinline__ float fdot2_(h2v a, h2v b, float c) {
#ifdef HAVE_FDOT2
    return __builtin_amdgcn_fdot2(a, b, c, false);
#else
    c = fmaf((float)a[0], (float)b[0], c);
    return fmaf((float)a[1], (float)b[1], c);
#endif
}

__device__ __forceinline__ float sig_(float x) { return 1.0f / (1.0f + __expf(-x)); }

__device__ __forceinline__ float tanh_(float x) {
    const float e = __expf(-2.0f * fabsf(x));
    const float r = (1.0f - e) / (1.0f + e);
    return copysignf(r, x);
}

// thread (m = tid>>3, q = tid&7): owns hidden unit m, K-slice q (8 rows of each
// 64-row half). Gate z obtained by in-wave butterfly over q (lane bits 0..2).
#define DOT_SELF(L, WSF)                                                        \
    _Pragma("unroll")                                                           \
    for (int b = 0; b < 4; ++b) {                                               \
        const h2v* hs = (const h2v*)&hbuf[p][L][b][0];                          \
        _Pragma("unroll")                                                       \
        for (int i = 0; i < 4; ++i) {                                           \
            const h2v sv = hs[q4 + i];                                          \
            _Pragma("unroll")                                                   \
            for (int g = 0; g < 4; ++g) acc[b][g] = fdot2_(WSF[g][i], sv, acc[b][g]); \
        }                                                                       \
    }

#define DOT_IN(L, WIN)                                                          \
    _Pragma("unroll")                                                           \
    for (int b = 0; b < 4; ++b) {                                               \
        const h2v* hi = (const h2v*)&hbuf[p ^ 1][(L) - 1][b][0];                \
        _Pragma("unroll")                                                       \
        for (int i = 0; i < 4; ++i) {                                           \
            const h2v iv = hi[q4 + i];                                          \
            _Pragma("unroll")                                                   \
            for (int g = 0; g < 4; ++g) acc[b][g] = fdot2_(WIN[g][i], iv, acc[b][g]); \
        }                                                                       \
    }

#define REDUCE16()                                                              \
    _Pragma("unroll")                                                           \
    for (int b = 0; b < 4; ++b)                                                 \
        _Pragma("unroll")                                                       \
        for (int g = 0; g < 4; ++g) {                                           \
            acc[b][g] += __shfl_xor(acc[b][g], 4, 64);                          \
            acc[b][g] += __shfl_xor(acc[b][g], 2, 64);                          \
            acc[b][g] += __shfl_xor(acc[b][g], 1, 64);                          \
        }

#define SELECTZ(L)                                                              \
    _Pragma("unroll")                                                           \
    for (int g = 0; g < 4; ++g) {                                               \
        const float v = (bsel == 0) ? acc[0][g] : (bsel == 1) ? acc[1][g]       \
                      : (bsel == 2) ? acc[2][g] : acc[3][g];                    \
        z[g] = v + bias[L][g];                                                  \
    }

#define APPLYGATE(L)                                                            \
    const float ig = sig_(z[0]), fg = sig_(z[1]);                               \
    const float gg = tanh_(z[2]), og = sig_(z[3]);                              \
    c##L = fmaf(fg, c##L, ig * gg);                                             \
    const float hn = og * tanh_(c##L);                                          \
    if (q < 4) ((_Float16*)&hbuf[p ^ 1][L][bsel][0])[m] = (_Float16)hn;

__global__ __launch_bounds__(NTHR, 1) void lstm4_dot2(
    const float* __restrict__ x,
    const float* __restrict__ W0, const float* __restrict__ B0,
    const float* __restrict__ W1, const float* __restrict__ B1,
    const float* __restrict__ W2, const float* __restrict__ B2,
    const float* __restrict__ W3, const float* __restrict__ B3,
    const float* __restrict__ ln_g, const float* __restrict__ ln_b,
    const float* __restrict__ Wout, const float* __restrict__ bout,
    float* __restrict__ out)
{
    __shared__ _Float16 hbuf[2][4][BBLK][HID];   // [parity][layer][b][m]  (4 KB)
    __shared__ float xall[BBLK][SEQ];            // 8 KB
    __shared__ float part[8][4][3];              // per-wave LN partials
    __shared__ float sconst[2];                  // S_gw, S_bw

    const int tid  = threadIdx.x;
    const int m    = tid >> 3;
    const int q    = tid & 7;
    const int q4   = q * 4;
    const int bsel = q & 3;
    const int lane = tid & 63;
    const int wv   = tid >> 6;
    const int bb   = blockIdx.x;

    // stage x
    for (int i = tid; i < BBLK * SEQ; i += NTHR)
        xall[i >> 9][i & 511] = x[bb * (BBLK * SEQ) + i];
    // zero h (both parities)
    for (int i = tid; i < 2 * 4 * BBLK * HID; i += NTHR)
        ((_Float16*)hbuf)[i] = (_Float16)0.0f;

    // LN/proj scalar constants (reduced once by wave 0)
    if (tid < 64) {
        float a = ln_g[tid] * Wout[tid];
        float b = ln_b[tid] * Wout[tid];
#pragma unroll
        for (int off = 32; off > 0; off >>= 1) {
            a += __shfl_xor(a, off, 64);
            b += __shfl_xor(b, off, 64);
        }
        if (tid == 0) { sconst[0] = a; sconst[1] = b; }
    }

    // per-thread constants & register weights (f16-packed pairs along K)
    float bias[4][4], wx[4];
    h2v wS0[4][4], wS1[4][4], wS2[4][4], wS3[4][4];
    h2v wI1[4][4], wI2[4][4], wI3[4][4];
#pragma unroll
    for (int g = 0; g < 4; ++g) {
        const int col = g * 64 + m;
        bias[0][g] = B0[col]; bias[1][g] = B1[col];
        bias[2][g] = B2[col]; bias[3][g] = B3[col];
        wx[g] = W0[col];                       // W0 row 0 = x weight
#pragma unroll
        for (int i = 0; i < 4; ++i) {
            const int r = q * 8 + 2 * i;
            wS0[g][i] = h2v{(_Float16)W0[(1 + r) * 256 + col], (_Float16)W0[(2 + r) * 256 + col]};
            wI1[g][i] = h2v{(_Float16)W1[r * 256 + col],        (_Float16)W1[(r + 1) * 256 + col]};
            wS1[g][i] = h2v{(_Float16)W1[(64 + r) * 256 + col], (_Float16)W1[(65 + r) * 256 + col]};
            wI2[g][i] = h2v{(_Float16)W2[r * 256 + col],        (_Float16)W2[(r + 1) * 256 + col]};
            wS2[g][i] = h2v{(_Float16)W2[(64 + r) * 256 + col], (_Float16)W2[(65 + r) * 256 + col]};
            wI3[g][i] = h2v{(_Float16)W3[r * 256 + col],        (_Float16)W3[(r + 1) * 256 + col]};
            wS3[g][i] = h2v{(_Float16)W3[(64 + r) * 256 + col], (_Float16)W3[(65 + r) * 256 + col]};
        }
    }
    const float gw = ln_g[m] * Wout[m];
    const float bo = bout[0];
    float c0 = 0.0f, c1 = 0.0f, c2 = 0.0f, c3 = 0.0f;

    __syncthreads();
    const float Sgw    = sconst[0];
    const float Sbw_bo = sconst[1] + bo;

    int p = 0;
    for (int t = 0; t < SEQ; ++t) {
        // ---------------- layer 0 (in = x scalar) ----------------
        {
            float acc[4][4] = {};
            DOT_SELF(0, wS0)
            REDUCE16()
            float z[4];
            SELECTZ(0)
            const float xv = xall[bsel][t];
#pragma unroll
            for (int g = 0; g < 4; ++g) z[g] = fmaf(xv, wx[g], z[g]);
            APPLYGATE(0)
        }
        __syncthreads();
        // ---------------- layer 1 ----------------
        {
            float acc[4][4] = {};
            DOT_SELF(1, wS1)
            DOT_IN(1, wI1)
            REDUCE16()
            float z[4];
            SELECTZ(1)
            APPLYGATE(1)
        }
        __syncthreads();
        // ---------------- layer 2 ----------------
        {
            float acc[4][4] = {};
            DOT_SELF(2, wS2)
            DOT_IN(2, wI2)
            REDUCE16()
            float z[4];
            SELECTZ(2)
            APPLYGATE(2)
        }
        __syncthreads();
        // ---------------- layer 3 + LN partials ----------------
        {
            float acc[4][4] = {};
            DOT_SELF(3, wS3)
            DOT_IN(3, wI3)
            REDUCE16()
            float z[4];
            SELECTZ(3)
            APPLYGATE(3)
            float v1 = (q < 4) ? hn : 0.0f;
            float v2 = v1 * hn;
            float v3 = v1 * gw;
#pragma unroll
            for (int off = 8; off <= 32; off <<= 1) {
                v1 += __shfl_xor(v1, off, 64);
                v2 += __shfl_xor(v2, off, 64);
                v3 += __shfl_xor(v3, off, 64);
            }
            if (lane < 4) {
                part[wv][lane][0] = v1;
                part[wv][lane][1] = v2;
                part[wv][lane][2] = v3;
            }
        }
        __syncthreads();
        // ---------------- LN combine + out store (wave 0) ----------------
        if (tid < 32) {
            const int b8 = tid >> 3, l8 = tid & 7;
            float s1 = part[l8][b8][0];
            float s2 = part[l8][b8][1];
            float s3 = part[l8][b8][2];
#pragma unroll
            for (int off = 1; off <= 4; off <<= 1) {
                s1 += __shfl_xor(s1, off, 64);
                s2 += __shfl_xor(s2, off, 64);
                s3 += __shfl_xor(s3, off, 64);
            }
            if (l8 == 0) {
                const float mu = s1 * (1.0f / 64.0f);
                float var = fmaf(s2, 1.0f / 64.0f, -mu * mu);
                var = fmaxf(var, 0.0f);
                const float rs = rsqrtf(var + 1e-5f);
                out[(bb * BBLK + b8) * SEQ + t] = fmaf(rs, fmaf(-mu, Sgw, s3), Sbw_bo);
            }
        }
        p ^= 1;
    }
}

extern "C" void kernel_launch(void* const* d_in, const int* in_sizes, int n_in,
                              void* d_out, int out_size, void* d_ws, size_t ws_size,
                              hipStream_t stream)
{
    const float* x    = (const float*)d_in[0];
    const float* W0   = (const float*)d_in[1];
    const float* B0   = (const float*)d_in[2];
    const float* W1   = (const float*)d_in[3];
    const float* B1   = (const float*)d_in[4];
    const float* W2   = (const float*)d_in[5];
    const float* B2   = (const float*)d_in[6];
    const float* W3   = (const float*)d_in[7];
    const float* B3   = (const float*)d_in[8];
    const float* ln_g = (const float*)d_in[9];
    const float* ln_b = (const float*)d_in[10];
    const float* Wout = (const float*)d_in[11];
    const float* bout = (const float*)d_in[12];
    float* out = (float*)d_out;

    lstm4_dot2<<<NBLK, NTHR, 0, stream>>>(x, W0, B0, W1, B1, W2, B2, W3, B3,
                                          ln_g, ln_b, Wout, bout, out);
}

// Round 4
// 969.559 us; speedup vs baseline: 3.9846x; 3.9846x over previous
//
#include <hip/hip_runtime.h>

#define SEQ   512
#define NTHR  512
#define NBLK  256

typedef _Float16 f16x8 __attribute__((ext_vector_type(8)));
typedef float    f32x4 __attribute__((ext_vector_type(4)));

#define MFMA(a, b, c) __builtin_amdgcn_mfma_f32_16x16x32_f16((a), (b), (c), 0, 0, 0)

__device__ __forceinline__ float sig_(float x) {
    return __builtin_amdgcn_rcpf(1.0f + __builtin_amdgcn_exp2f(x * -1.4426950408889634f));
}
// tanh(x) = 2*sigmoid(2x) - 1 ; saturates cleanly at +/-1 for large |x|
__device__ __forceinline__ float tanh_(float x) {
    return fmaf(2.0f, __builtin_amdgcn_rcpf(1.0f + __builtin_amdgcn_exp2f(x * -2.8853900817779268f)), -1.0f);
}

// gates from accumulator regs (bias already folded into acc init)
#define GATES_TILE(ACC, CREF, HN)                                              \
    {                                                                          \
        const float gi = sig_(ACC[0]);                                         \
        const float gf = sig_(ACC[1]);                                         \
        const float gg = tanh_(ACC[2]);                                        \
        const float go = sig_(ACC[3]);                                         \
        CREF = fmaf(gf, CREF, gi * gg);                                        \
        HN   = go * tanh_(CREF);                                               \
    }

// layer L (1..3): in = h[L-1] (new parity), self = h[L] (old parity)
#define DO_LAYER(L, WF, BIASV)                                                 \
    {                                                                          \
        const char* bIn   = bNew + ((L) - 1) * 512;                            \
        const char* bSelf = bOld + (L) * 512;                                  \
        const f16x8 hI0 = *(const f16x8*)(bIn + a0);                           \
        const f16x8 hI1 = *(const f16x8*)(bIn + a1);                           \
        const f16x8 hS0 = *(const f16x8*)(bSelf + a0);                         \
        const f16x8 hS1 = *(const f16x8*)(bSelf + a1);                         \
        f32x4 acc0, acc1;                                                      \
        _Pragma("unroll")                                                      \
        for (int r = 0; r < 4; ++r) { acc0[r] = BIASV[0][r]; acc1[r] = BIASV[1][r]; } \
        acc0 = MFMA(WF[0][0], hI0, acc0);  acc1 = MFMA(WF[1][0], hI0, acc1);   \
        acc0 = MFMA(WF[0][1], hI1, acc0);  acc1 = MFMA(WF[1][1], hI1, acc1);   \
        acc0 = MFMA(WF[0][2], hS0, acc0);  acc1 = MFMA(WF[1][2], hS0, acc1);   \
        acc0 = MFMA(WF[0][3], hS1, acc0);  acc1 = MFMA(WF[1][3], hS1, acc1);   \
        float cv0 = cst[L][0], cv1 = cst[L][1];                                \
        GATES_TILE(acc0, cv0, hn0)                                             \
        GATES_TILE(acc1, cv1, hn1)                                             \
        cst[L][0] = cv0; cst[L][1] = cv1;                                      \
        char* hw = bNew + (L) * 512;                                           \
        if (gl) { *(_Float16*)(hw + wr0) = (_Float16)hn0;                      \
                  *(_Float16*)(hw + wr1) = (_Float16)hn1; }                    \
    }

__global__ __launch_bounds__(NTHR, 2) void lstm4_mfma(
    const float* __restrict__ x,
    const float* __restrict__ W0, const float* __restrict__ B0,
    const float* __restrict__ W1, const float* __restrict__ B1,
    const float* __restrict__ W2, const float* __restrict__ B2,
    const float* __restrict__ W3, const float* __restrict__ B3,
    const float* __restrict__ ln_g, const float* __restrict__ ln_b,
    const float* __restrict__ Wout, const float* __restrict__ bout,
    float* __restrict__ out)
{
    // h state: [parity][layer][b(4)][k(64) 16B-chunk-swizzled], f16
    __shared__ __align__(16) _Float16 hbuf[2][4][4][64];
    __shared__ float xall[4][SEQ];
    __shared__ float part[8][4][4];
    __shared__ float sconst[2];

    const int tid  = threadIdx.x;
    const int lane = tid & 63;
    const int w    = tid >> 6;          // wave 0..7
    const int lam  = lane >> 4;         // 0..3
    const int bc   = lane & 15;
    const int br   = bc & 3;            // clamped batch row (broadcast pad lanes)
    const int bb   = blockIdx.x;
    const int T0   = 2 * w, T1 = 2 * w + 1;

    // ---- stage x, zero h ----
    for (int i = tid; i < 4 * SEQ; i += NTHR)
        xall[i >> 9][i & 511] = x[bb * 4 * SEQ + i];
    for (int i = tid; i < 2 * 4 * 4 * 64; i += NTHR)
        ((_Float16*)hbuf)[i] = (_Float16)0.0f;
    if (tid < 64) {
        float a = ln_g[tid] * Wout[tid];
        float b = ln_b[tid] * Wout[tid];
#pragma unroll
        for (int off = 32; off > 0; off >>= 1) {
            a += __shfl_xor(a, off, 64);
            b += __shfl_xor(b, off, 64);
        }
        if (tid == 0) { sconst[0] = a; sconst[1] = b; }
    }

    // ---- A-fragments: W^T, gate-permuted rows (row R -> m=R>>2, gate=R&3) ----
    // A-frag: lane provides row rho=lane&15 of its tile, k = kt*32 + lam*8 + e
    const int rho   = bc;
    const int colA0 = (rho & 3) * 64 + T0 * 4 + (rho >> 2);
    const int colA1 = (rho & 3) * 64 + T1 * 4 + (rho >> 2);

    f16x8 wf0[2][2], wf1[2][4], wf2[2][4], wf3[2][4];
#pragma unroll
    for (int kt = 0; kt < 2; ++kt) {
        const int kb = 1 + kt * 32 + lam * 8;   // W0 rows 1..64 = h weights
#pragma unroll
        for (int e = 0; e < 8; ++e) {
            wf0[0][kt][e] = (_Float16)W0[(kb + e) * 256 + colA0];
            wf0[1][kt][e] = (_Float16)W0[(kb + e) * 256 + colA1];
        }
    }
#pragma unroll
    for (int kt = 0; kt < 4; ++kt) {
        const int kb = kt * 32 + lam * 8;       // rows 0..63 = in-h, 64..127 = self-h
#pragma unroll
        for (int e = 0; e < 8; ++e) {
            wf1[0][kt][e] = (_Float16)W1[(kb + e) * 256 + colA0];
            wf1[1][kt][e] = (_Float16)W1[(kb + e) * 256 + colA1];
            wf2[0][kt][e] = (_Float16)W2[(kb + e) * 256 + colA0];
            wf2[1][kt][e] = (_Float16)W2[(kb + e) * 256 + colA1];
            wf3[0][kt][e] = (_Float16)W3[(kb + e) * 256 + colA0];
            wf3[1][kt][e] = (_Float16)W3[(kb + e) * 256 + colA1];
        }
    }

    // ---- bias / wx / LN constants (C-lane view: reg r = gate, m = T*4+lam) ----
    float bias0[2][4], bias1[2][4], bias2[2][4], bias3[2][4], wx[2][4];
#pragma unroll
    for (int r = 0; r < 4; ++r) {
        const int c0 = r * 64 + T0 * 4 + lam;
        const int c1 = r * 64 + T1 * 4 + lam;
        bias0[0][r] = B0[c0]; bias0[1][r] = B0[c1];
        bias1[0][r] = B1[c0]; bias1[1][r] = B1[c1];
        bias2[0][r] = B2[c0]; bias2[1][r] = B2[c1];
        bias3[0][r] = B3[c0]; bias3[1][r] = B3[c1];
        wx[0][r] = W0[c0];    wx[1][r] = W0[c1];    // W0 row 0 (x weight)
    }
    const int   m0  = T0 * 4 + lam, m1 = T1 * 4 + lam;
    const float gw0 = ln_g[m0] * Wout[m0];
    const float gw1 = ln_g[m1] * Wout[m1];
    const float bo  = bout[0];

    // ---- LDS byte offsets (within one [4][64] f16 layer buffer) ----
    // read: B-frag, pad lanes broadcast row br; chunk swizzle kc^br
    const int a0  = br * 128 + ((lam)     ^ br) * 16;          // kt=0
    const int a1  = br * 128 + ((4 + lam) ^ br) * 16;          // kt=1
    // write: h[bc][m], chunk swizzle (m>>3)^bc  (valid for bc<4, guarded)
    const int wr0 = bc * 128 + (((m0 >> 3) ^ bc) * 16) + (m0 & 7) * 2;
    const int wr1 = bc * 128 + (((m1 >> 3) ^ bc) * 16) + (m1 & 7) * 2;
    const bool gl = (bc < 4);

    float cst[4][2] = {{0.f,0.f},{0.f,0.f},{0.f,0.f},{0.f,0.f}};
    char* const hb = (char*)hbuf;

    __syncthreads();
    const float Sgw = sconst[0];
    const float Sbw = sconst[1] + bo;

    int p = 0;
    for (int t = 0; t < SEQ; ++t) {
        char* bOld = hb + p * 2048;
        char* bNew = hb + (p ^ 1) * 2048;
        float hn0 = 0.0f, hn1 = 0.0f;

        // ================= layer 0 (in = x scalar, self-h K=64) =================
        {
            const f16x8 hS0 = *(const f16x8*)(bOld + a0);
            const f16x8 hS1 = *(const f16x8*)(bOld + a1);
            const float xv  = xall[br][t];
            f32x4 acc0, acc1;
#pragma unroll
            for (int r = 0; r < 4; ++r) {
                acc0[r] = fmaf(xv, wx[0][r], bias0[0][r]);
                acc1[r] = fmaf(xv, wx[1][r], bias0[1][r]);
            }
            acc0 = MFMA(wf0[0][0], hS0, acc0);  acc1 = MFMA(wf0[1][0], hS0, acc1);
            acc0 = MFMA(wf0[0][1], hS1, acc0);  acc1 = MFMA(wf0[1][1], hS1, acc1);
            float cv0 = cst[0][0], cv1 = cst[0][1];
            GATES_TILE(acc0, cv0, hn0)
            GATES_TILE(acc1, cv1, hn1)
            cst[0][0] = cv0; cst[0][1] = cv1;
            char* hw = bNew;
            if (gl) { *(_Float16*)(hw + wr0) = (_Float16)hn0;
                      *(_Float16*)(hw + wr1) = (_Float16)hn1; }
        }
        __syncthreads();

        DO_LAYER(1, wf1, bias1)
        __syncthreads();
        DO_LAYER(2, wf2, bias2)
        __syncthreads();
        DO_LAYER(3, wf3, bias3)

        // ---- LN partials (layer-3 hn): per-wave sums over its 8 m values ----
        {
            float v1 = hn0 + hn1;
            float v2 = fmaf(hn0, hn0, hn1 * hn1);
            float v3 = fmaf(hn0, gw0, hn1 * gw1);
            if (!gl) { v1 = 0.0f; v2 = 0.0f; v3 = 0.0f; }
            v1 += __shfl_xor(v1, 16, 64); v2 += __shfl_xor(v2, 16, 64); v3 += __shfl_xor(v3, 16, 64);
            v1 += __shfl_xor(v1, 32, 64); v2 += __shfl_xor(v2, 32, 64); v3 += __shfl_xor(v3, 32, 64);
            if (lane < 4) {
                part[w][lane][0] = v1;
                part[w][lane][1] = v2;
                part[w][lane][2] = v3;
            }
        }
        __syncthreads();

        // ---- LN combine + projection + store (wave 0, 32 lanes) ----
        if (tid < 32) {
            const int w8 = tid & 7, b = tid >> 3;
            float s1 = part[w8][b][0];
            float s2 = part[w8][b][1];
            float s3 = part[w8][b][2];
            s1 += __shfl_xor(s1, 1, 64); s2 += __shfl_xor(s2, 1, 64); s3 += __shfl_xor(s3, 1, 64);
            s1 += __shfl_xor(s1, 2, 64); s2 += __shfl_xor(s2, 2, 64); s3 += __shfl_xor(s3, 2, 64);
            s1 += __shfl_xor(s1, 4, 64); s2 += __shfl_xor(s2, 4, 64); s3 += __shfl_xor(s3, 4, 64);
            if (w8 == 0) {
                const float mu = s1 * (1.0f / 64.0f);
                float var = fmaf(s2, 1.0f / 64.0f, -mu * mu);
                var = fmaxf(var, 0.0f);
                const float rs = rsqrtf(var + 1e-5f);
                out[(bb * 4 + b) * SEQ + t] = fmaf(rs, fmaf(-mu, Sgw, s3), Sbw);
            }
        }
        p ^= 1;
    }
}

extern "C" void kernel_launch(void* const* d_in, const int* in_sizes, int n_in,
                              void* d_out, int out_size, void* d_ws, size_t ws_size,
                              hipStream_t stream)
{
    const float* x    = (const float*)d_in[0];
    const float* W0   = (const float*)d_in[1];
    const float* B0   = (const float*)d_in[2];
    const float* W1   = (const float*)d_in[3];
    const float* B1   = (const float*)d_in[4];
    const float* W2   = (const float*)d_in[5];
    const float* B2   = (const float*)d_in[6];
    const float* W3   = (const float*)d_in[7];
    const float* B3   = (const float*)d_in[8];
    const float* ln_g = (const float*)d_in[9];
    const float* ln_b = (const float*)d_in[10];
    const float* Wout = (const float*)d_in[11];
    const float* bout = (const float*)d_in[12];
    float* out = (float*)d_out;

    lstm4_mfma<<<NBLK, NTHR, 0, stream>>>(x, W0, B0, W1, B1, W2, B2, W3, B3,
                                          ln_g, ln_b, Wout, bout, out);
}